// Round 1
// baseline (36.868 us; speedup 1.0000x reference)
//
#include <hip/hip_runtime.h>

namespace {
constexpr int   kB     = 256;
constexpr int   kN     = 50;
constexpr int   kD     = 128;
constexpr int   kRP    = 132;        // padded LDS row stride in floats (132%8==4 -> quad rotation)
constexpr float kNeg   = -9.0e15f;
constexpr float kSlope = 0.2f;
}

__global__ __launch_bounds__(256)
void gat_fused_kernel(const float* __restrict__ hidden,
                      const int*   __restrict__ adj,
                      const float* __restrict__ a0,
                      const float* __restrict__ a1,
                      const float* __restrict__ a2,
                      const float* __restrict__ a3,
                      float* __restrict__ out)
{
    __shared__ float hsh[kN * kRP];      // 50 x 128 staged hidden row-block, padded
    __shared__ float wsh[4 * kRP];       // 4 relation vectors
    __shared__ float ash[4][2][64];      // per-wave attention rows (2 rows in flight)

    const int b    = blockIdx.x;
    const int tid  = threadIdx.x;
    const int lane = tid & 63;
    const int wid  = tid >> 6;

    // ---- stage hidden[b] into LDS (float4, coalesced) ----
    const float4* hg = reinterpret_cast<const float4*>(hidden + (size_t)b * (kN * kD));
    for (int idx = tid; idx < kN * (kD / 4); idx += 256) {
        const int j  = idx >> 5;    // row   (32 float4 per row)
        const int d4 = idx & 31;    // float4 column
        const float4 v = hg[idx];
        *reinterpret_cast<float4*>(&hsh[j * kRP + d4 * 4]) = v;
    }
    if (tid < kD) {
        wsh[0 * kRP + tid] = a0[tid];
        wsh[1 * kRP + tid] = a1[tid];
        wsh[2 * kRP + tid] = a2[tid];
        wsh[3 * kRP + tid] = a3[tid];
    }
    __syncthreads();

    const int*  adjb = adj + (size_t)b * (kN * kN);
    float*      outb = out + (size_t)b * (kN * kD);

    // ---- per-wave row-pair loop: scores -> softmax -> PV, no barriers ----
    for (int p = wid; p < kN / 2; p += 4) {
        const int  i0 = 2 * p;
        const int  i1 = 2 * p + 1;
        const int  j  = lane;
        const bool jv = (j < kN);

        int k0 = 0, k1 = 0;
        if (jv) {
            k0 = adjb[i0 * kN + j];
            k1 = adjb[i1 * kN + j];
        }
        const bool v0 = jv && (k0 >= 1) && (k0 <= 4);
        const bool v1 = jv && (k1 >= 1) && (k1 <= 4);
        const int  w0 = v0 ? (k0 - 1) : 0;
        const int  w1 = v1 ? (k1 - 1) : 0;

        float s0 = kNeg, s1 = kNeg;
        if (jv) {
            const float4* hj4 = reinterpret_cast<const float4*>(&hsh[j  * kRP]);
            const float4* ha4 = reinterpret_cast<const float4*>(&hsh[i0 * kRP]);
            const float4* hb4 = reinterpret_cast<const float4*>(&hsh[i1 * kRP]);
            const float4* wa4 = reinterpret_cast<const float4*>(&wsh[w0 * kRP]);
            const float4* wb4 = reinterpret_cast<const float4*>(&wsh[w1 * kRP]);
            float acc0 = 0.f, acc1 = 0.f;
            #pragma unroll 8
            for (int d4 = 0; d4 < kD / 4; ++d4) {
                const float4 hj = hj4[d4];
                const float4 ha = ha4[d4];
                const float4 hb = hb4[d4];
                const float4 wa = wa4[d4];
                const float4 wb = wb4[d4];
                acc0 += (ha.x * hj.x) * wa.x + (ha.y * hj.y) * wa.y
                      + (ha.z * hj.z) * wa.z + (ha.w * hj.w) * wa.w;
                acc1 += (hb.x * hj.x) * wb.x + (hb.y * hj.y) * wb.y
                      + (hb.z * hj.z) * wb.z + (hb.w * hj.w) * wb.w;
            }
            const float l0 = (acc0 > 0.f) ? acc0 : kSlope * acc0;
            const float l1 = (acc1 > 0.f) ? acc1 : kSlope * acc1;
            s0 = v0 ? l0 : kNeg;
            s1 = v1 ? l1 : kNeg;
        }

        // ---- wave-parallel softmax over j (64-lane reduce) ----
        float m0 = s0, m1 = s1;
        #pragma unroll
        for (int o = 32; o; o >>= 1) {
            m0 = fmaxf(m0, __shfl_xor(m0, o));
            m1 = fmaxf(m1, __shfl_xor(m1, o));
        }
        const float e0 = jv ? __expf(s0 - m0) : 0.f;  // all-masked row: exp(0)=1 -> uniform, matches ref
        const float e1 = jv ? __expf(s1 - m1) : 0.f;
        float t0 = e0, t1 = e1;
        #pragma unroll
        for (int o = 32; o; o >>= 1) {
            t0 += __shfl_xor(t0, o);
            t1 += __shfl_xor(t1, o);
        }
        const float at0 = e0 / t0;
        const float at1 = e1 / t1;

        // stash attention rows for broadcast re-read (wave-synchronous, same wave only)
        ash[wid][0][lane] = at0;
        ash[wid][1][lane] = at1;

        // ---- PV: out[i,:] = sum_j attn[i,j] * h[j,:]; lane owns 2 d's ----
        float o0x = 0.f, o0y = 0.f, o1x = 0.f, o1y = 0.f;
        #pragma unroll 5
        for (int jj = 0; jj < kN; ++jj) {
            const float av0 = ash[wid][0][jj];
            const float av1 = ash[wid][1][jj];
            const float2 h2 = *reinterpret_cast<const float2*>(&hsh[jj * kRP + 2 * lane]);
            o0x += av0 * h2.x;  o0y += av0 * h2.y;
            o1x += av1 * h2.x;  o1y += av1 * h2.y;
        }
        float2 r0; r0.x = o0x; r0.y = o0y;
        float2 r1; r1.x = o1x; r1.y = o1y;
        *reinterpret_cast<float2*>(&outb[i0 * kD + 2 * lane]) = r0;
        *reinterpret_cast<float2*>(&outb[i1 * kD + 2 * lane]) = r1;
    }
}

extern "C" void kernel_launch(void* const* d_in, const int* in_sizes, int n_in,
                              void* d_out, int out_size, void* d_ws, size_t ws_size,
                              hipStream_t stream) {
    const float* hidden = reinterpret_cast<const float*>(d_in[0]);
    const int*   adjp   = reinterpret_cast<const int*>(d_in[1]);
    const float* a0     = reinterpret_cast<const float*>(d_in[2]);
    const float* a1     = reinterpret_cast<const float*>(d_in[3]);
    const float* a2     = reinterpret_cast<const float*>(d_in[4]);
    const float* a3     = reinterpret_cast<const float*>(d_in[5]);
    float*       outp   = reinterpret_cast<float*>(d_out);

    gat_fused_kernel<<<dim3(kB), dim3(256), 0, stream>>>(
        hidden, adjp, a0, a1, a2, a3, outp);
}